// Round 6
// baseline (380.221 us; speedup 1.0000x reference)
//
#include <hip/hip_runtime.h>
#include <math.h>

typedef __attribute__((ext_vector_type(8))) short short8;
typedef __attribute__((ext_vector_type(4))) float floatx4;

#define BB 32
#define CC 128
#define OO 256
#define HH 56
#define WW 56
#define HWSZ 3136
#define NPIX 100352
#define WELEM 294912
#define QN 65535.0f
#define QINV (1.0f/65535.0f)

// ---- workspace layout (bytes) ----
#define MAXB_OFF   0
#define CFLAG_OFF  128                        // uint: any coef != 0 ?
#define WTERM_OFF  256
#define COEF_OFF   2048                       // float [9][128]
#define KEFF_OFF   8192                       // bf16 frag-order [8 ob][36 steps][2KB] = 589824 B
#define YSQ_OFF    598016                     // float [100352] = 401408 B
#define XQP_OFF    1048576                    // bf16 [32][58][64][128] = 30408704 B
#define XQP_BYTES  30408704ull
#define WS_NEED    (XQP_OFF + XQP_BYTES)
// fallback layout
#define KEFF32_OFF 8192                       // float [9*128][256] = 1179648

__device__ __forceinline__ float quant_x(float v) {
    v = fminf(fmaxf(v, 0.0f), 1.0f);
    return rintf(v * QN) * QINV;              // round-half-even == jnp.round
}

__device__ __forceinline__ unsigned short f2bf(float f) {
    unsigned u = __float_as_uint(f);
    u += 0x7fffu + ((u >> 16) & 1u);          // RNE
    return (unsigned short)(u >> 16);
}

__device__ __forceinline__ void gl16(const void* g, void* l) {
    __builtin_amdgcn_global_load_lds(
        (const __attribute__((address_space(1))) unsigned char*)g,
        (__attribute__((address_space(3))) unsigned char*)l, 16, 0, 0);
}

// ---------- max |w| ----------
__global__ void kmax_kernel(const float* __restrict__ w, unsigned* __restrict__ maxout) {
    int i = blockIdx.x * blockDim.x + threadIdx.x;
    float m = 0.0f;
    for (int idx = i; idx < WELEM; idx += gridDim.x * blockDim.x)
        m = fmaxf(m, fabsf(w[idx]));
    #pragma unroll
    for (int off = 32; off; off >>= 1)
        m = fmaxf(m, __shfl_down(m, off));
    __shared__ float red[4];
    if ((threadIdx.x & 63) == 0) red[threadIdx.x >> 6] = m;
    __syncthreads();
    if (threadIdx.x == 0) {
        m = fmaxf(fmaxf(red[0], red[1]), fmaxf(red[2], red[3]));
        atomicMax(maxout, __float_as_uint(m));
    }
}

// ---------- prep: bf16 k_eff scattered into MFMA-fragment order + coef + flag + w_term ----------
// Layout: [ob = o>>5][step = kk*4 + (c>>5)] 2KB tiles; within (lo=o&31, c&31):
//   byte = mf*1024 + (kg*16 + l15)*16 + e*2,  mf=(lo>>4)&1, l15=lo&15, kg=(c>>3)&3, e=c&7
__global__ void kprep_kernel(const float* __restrict__ wt, const float* __restrict__ phases,
                             const float* __restrict__ disks, const unsigned* __restrict__ maxbits,
                             unsigned short* __restrict__ kefft, float* __restrict__ coef,
                             unsigned* __restrict__ cflag, float* __restrict__ wterm) {
    int idx = blockIdx.x * blockDim.x + threadIdx.x;   // over [o][c][kh][kw]
    if (idx >= WELEM) return;
    int kk = idx % 9;
    int c  = (idx / 9) % CC;
    int o  = idx / (9 * CC);
    float M = tanhf(__uint_as_float(*maxbits));
    float t = tanhf(wt[idx]);
    float v = t / (2.0f * M) + 0.5f;
    float wq = rintf(v * QN) * QINV;
    int pidx = c * 9 + kk;
    float s  = sinf(phases[pidx]);
    float d0 = disks[pidx * 2 + 0];
    float d1 = disks[pidx * 2 + 1];
    float kv = wq * (s * (d0 + d1) * 0.5f);

    int step = kk * 4 + (c >> 5);
    int ob = o >> 5, lo = o & 31;
    int mf = (lo >> 4) & 1, l15 = lo & 15;
    int kg = (c >> 3) & 3, e = c & 7;
    size_t byte = (size_t)ob * 73728 + (size_t)step * 2048
                + mf * 1024 + (kg * 16 + l15) * 16 + e * 2;
    kefft[byte >> 1] = f2bf(kv);

    float cf = (d0 - d1) * 0.25f;
    if (o == 0) {
        coef[kk * CC + c] = cf;
        if (cf != 0.0f) atomicOr(cflag, 1u);
    }
    float contrib = wq * wq * cf;
    if (contrib != 0.0f) atomicAdd(wterm + o, contrib);
}

// ---------- zero only the padding border of xqp ----------
__global__ __launch_bounds__(256) void kborder_kernel(unsigned short* __restrict__ xqp) {
    int t = threadIdx.x;
    int id = blockIdx.x * 256 + t;          // [0, 9216): 576 border px * 16 chunks
    int b = blockIdx.y;
    int pxi = id >> 4, chunk = id & 15;
    int h, w;
    if (pxi < 128) { h = (pxi >> 6) * 57; w = pxi & 63; }
    else { int r = pxi - 128; h = 1 + (r >> 3); int wi = r & 7; w = wi == 0 ? 0 : 56 + wi; }
    short8 z = (short8)0;
    *reinterpret_cast<short8*>((char*)xqp + (size_t)b * 3801088ull
                               + ((size_t)(h * 64 + w)) * 256 + chunk * 16) = z;
}

// ---------- quantize + NCHW->padded-NHWC bf16 transpose ----------
__global__ __launch_bounds__(256) void kxqpad_kernel(const float* __restrict__ x,
                                                     unsigned short* __restrict__ xqp) {
    __shared__ __align__(16) unsigned short tile[64][136];   // [hw][c]
    int t = threadIdx.x;
    int b = blockIdx.y;
    int hw0 = blockIdx.x * 64;
    const float* xb = x + (size_t)b * (CC * HWSZ) + hw0;
    #pragma unroll
    for (int rep = 0; rep < 32; ++rep) {
        int lin = rep * 256 + t;
        int c = lin >> 6, j = lin & 63;
        float v = xb[(size_t)c * HWSZ + j];                  // coalesced
        tile[j][c] = f2bf(quant_x(v));
    }
    __syncthreads();
    unsigned short* xq_b = xqp + (size_t)b * (58 * 64 * 128);
    #pragma unroll
    for (int rep = 0; rep < 4; ++rep) {
        int lin = rep * 256 + t;
        int c16 = lin & 15, j = lin >> 4;
        int hw = hw0 + j;
        int h = hw / WW, w = hw - h * WW;
        short8 v = *reinterpret_cast<const short8*>(&tile[j][c16 * 8]);
        *reinterpret_cast<short8*>(xq_b + ((size_t)((h + 1) * 64 + (w + 1))) * 128 + c16 * 8) = v;
    }
}

// ---------- y_sq = conv(x_q^2, coef); exact zero fast path when all coef==0 ----------
__global__ __launch_bounds__(256) void ysq_kernel(const float* __restrict__ x,
                                                  const float* __restrict__ coef,
                                                  const unsigned* __restrict__ cflag,
                                                  float* __restrict__ ysq) {
    int t = threadIdx.x;
    int P = blockIdx.x * 256 + t;
    if (*cflag == 0u) {            // wave-uniform: ideal disks -> y_sq is exactly 0
        ysq[P] = 0.0f;
        return;
    }
    __shared__ float cf[9 * CC];
    for (int i = t; i < 9 * CC; i += 256) cf[i] = coef[i];
    __syncthreads();
    int b = P / HWSZ; int hw = P - b * HWSZ;
    int h = hw / WW;  int w = hw - h * WW;
    const float* xb = x + (size_t)b * (CC * HWSZ);
    float s2 = 0.0f;
    #pragma unroll
    for (int kk = 0; kk < 9; ++kk) {
        int dh = kk / 3 - 1, dw = kk % 3 - 1;
        int ih = h + dh, iw = w + dw;
        bool valid = ((unsigned)ih < HH) && ((unsigned)iw < WW);
        int ihc = min(max(ih, 0), HH - 1), iwc = min(max(iw, 0), WW - 1);
        const float* xp = xb + ihc * WW + iwc;
        float fm = valid ? 1.0f : 0.0f;
        const float* cp = cf + kk * CC;
        #pragma unroll 4
        for (int c = 0; c < CC; ++c) {
            float xv = quant_x(xp[(size_t)c * HWSZ]) * fm;
            s2 = fmaf(xv * xv, cp[c], s2);
        }
    }
    ysq[P] = s2;
}

// ---------- MFMA conv: A-resident-in-LDS, B streamed global->reg, NO in-loop barriers ----------
// Block: 32 o (A slice, 72KB LDS, loaded once) x 256 px (4 indep waves x 64 px).
// Per wave per k-step (32): 2 A ds_read_b128 (linear) + 4 B global 16B loads + 8 MFMA.
// Fully unrolled 36-step k-loop; compiler software-pipelines freely (no barriers).
// 2 blocks/CU (144KB LDS) -> 8 waves/CU, independent progress.
__global__ __launch_bounds__(256, 4) void oconv_kernel(
        const unsigned short* __restrict__ xqp,
        const unsigned short* __restrict__ keff,
        const float* __restrict__ ysq,
        const float* __restrict__ wterm,
        float* __restrict__ out) {
    extern __shared__ __align__(16) char alds[];   // 73728 B: A [36 steps][2KB frag-order]
    const int t  = threadIdx.x;
    const int bx = blockIdx.x;                     // px tile (392 tiles of 256)
    const int ob = blockIdx.y;                     // o block (8 blocks of 32)

    // stage A slice (32 o x 1152 k) into LDS, fragment order, lane-linear
    {
        const char* ga = (const char*)keff + (size_t)ob * 73728 + t * 16;
        char* la = alds + t * 16;
        #pragma unroll
        for (int i = 0; i < 18; ++i)
            gl16(ga + i * 4096, la + i * 4096);
    }

    const int l15 = t & 15;
    const int kg  = (t >> 4) & 3;
    const int wv_ = t >> 6;                        // wave id 0..3

    // per-lane global B base byte-addresses for the 4 px fragments (incl. kg offset)
    const char* xb = (const char*)xqp;
    long pxb[4];
    #pragma unroll
    for (int nf = 0; nf < 4; ++nf) {
        int P = bx * 256 + wv_ * 64 + nf * 16 + l15;
        int b = P / HWSZ, hw = P - b * HWSZ;
        int h = hw / WW,  ww = hw - h * WW;
        pxb[nf] = ((long)((b * 58 + h + 1) * 64 + (ww + 1))) * 256 + kg * 16;
    }

    floatx4 acc[2][4];
    #pragma unroll
    for (int i = 0; i < 2; ++i)
        #pragma unroll
        for (int j = 0; j < 4; ++j) acc[i][j] = (floatx4)0.0f;

    __syncthreads();                               // A resident (vmcnt(0) + barrier)

    const int lane16 = (t & 63) * 16;
    #pragma unroll
    for (int kk = 0; kk < 9; ++kk) {
        const int dh = kk / 3, dw = kk - dh * 3;
        const long bo = (long)((dh - 1) * 64 + (dw - 1)) * 256;
        const char* bp0 = xb + pxb[0] + bo;
        const char* bp1 = xb + pxb[1] + bo;
        const char* bp2 = xb + pxb[2] + bo;
        const char* bp3 = xb + pxb[3] + bo;
        #pragma unroll
        for (int cs = 0; cs < 4; ++cs) {
            const int s = kk * 4 + cs;
            short8 b0 = *reinterpret_cast<const short8*>(bp0 + cs * 64);
            short8 b1 = *reinterpret_cast<const short8*>(bp1 + cs * 64);
            short8 b2 = *reinterpret_cast<const short8*>(bp2 + cs * 64);
            short8 b3 = *reinterpret_cast<const short8*>(bp3 + cs * 64);
            short8 a0 = *reinterpret_cast<const short8*>(alds + s * 2048 + lane16);
            short8 a1 = *reinterpret_cast<const short8*>(alds + s * 2048 + 1024 + lane16);
            acc[0][0] = __builtin_amdgcn_mfma_f32_16x16x32_bf16(a0, b0, acc[0][0], 0, 0, 0);
            acc[0][1] = __builtin_amdgcn_mfma_f32_16x16x32_bf16(a0, b1, acc[0][1], 0, 0, 0);
            acc[0][2] = __builtin_amdgcn_mfma_f32_16x16x32_bf16(a0, b2, acc[0][2], 0, 0, 0);
            acc[0][3] = __builtin_amdgcn_mfma_f32_16x16x32_bf16(a0, b3, acc[0][3], 0, 0, 0);
            acc[1][0] = __builtin_amdgcn_mfma_f32_16x16x32_bf16(a1, b0, acc[1][0], 0, 0, 0);
            acc[1][1] = __builtin_amdgcn_mfma_f32_16x16x32_bf16(a1, b1, acc[1][1], 0, 0, 0);
            acc[1][2] = __builtin_amdgcn_mfma_f32_16x16x32_bf16(a1, b2, acc[1][2], 0, 0, 0);
            acc[1][3] = __builtin_amdgcn_mfma_f32_16x16x32_bf16(a1, b3, acc[1][3], 0, 0, 0);
        }
    }

    // epilogue: D row = o (row=(lane>>4)*4+j), col = px (col=lane&15)
    float wvv[2][4];
    #pragma unroll
    for (int mf = 0; mf < 2; ++mf)
        #pragma unroll
        for (int j = 0; j < 4; ++j)
            wvv[mf][j] = wterm[ob * 32 + mf * 16 + kg * 4 + j];

    #pragma unroll
    for (int nf = 0; nf < 4; ++nf) {
        int P = bx * 256 + wv_ * 64 + nf * 16 + l15;
        int b = P / HWSZ; int hw = P - b * HWSZ;
        float yv = ysq[P];
        float* op = out + (size_t)b * (OO * HWSZ) + hw;
        #pragma unroll
        for (int mf = 0; mf < 2; ++mf)
            #pragma unroll
            for (int j = 0; j < 4; ++j) {
                int o = ob * 32 + mf * 16 + kg * 4 + j;
                op[(size_t)o * HWSZ] = acc[mf][nf][j] + yv + wvv[mf][j];
            }
    }
}

// ================= fallback path (fp32 direct conv) =================
__global__ void kprep32_kernel(const float* __restrict__ wt, const float* __restrict__ phases,
                               const float* __restrict__ disks, const unsigned* __restrict__ maxbits,
                               float* __restrict__ keff, float* __restrict__ coef,
                               float* __restrict__ wterm) {
    int idx = blockIdx.x * blockDim.x + threadIdx.x;
    if (idx >= WELEM) return;
    int kk = idx % 9;
    int c  = (idx / 9) % CC;
    int o  = idx / (9 * CC);
    float M = tanhf(__uint_as_float(*maxbits));
    float t = tanhf(wt[idx]);
    float v = t / (2.0f * M) + 0.5f;
    float wq = rintf(v * QN) * QINV;
    int pidx = c * 9 + kk;
    float s  = sinf(phases[pidx]);
    float d0 = disks[pidx * 2 + 0];
    float d1 = disks[pidx * 2 + 1];
    keff[(kk * CC + c) * OO + o] = wq * (s * (d0 + d1) * 0.5f);
    float cf = (d0 - d1) * 0.25f;
    if (o == 0) coef[kk * CC + c] = cf;
    float contrib = wq * wq * cf;
    if (contrib != 0.0f) atomicAdd(wterm + o, contrib);
}

__global__ __launch_bounds__(256) void kconv32_kernel(
        const float* __restrict__ xsrc, const float* __restrict__ keff,
        const float* __restrict__ coef, const float* __restrict__ wterm,
        float* __restrict__ out) {
    int t   = blockIdx.x * 256 + threadIdx.x;
    int ocb = blockIdx.y * 16;
    int b   = t / HWSZ;
    int rem = t - b * HWSZ;
    int h   = rem / WW;
    int w   = rem - h * WW;
    float acc[16];
    #pragma unroll
    for (int i = 0; i < 16; ++i) acc[i] = 0.0f;
    float s2 = 0.0f;
    const float* xb = xsrc + (size_t)b * (CC * HWSZ);
    #pragma unroll
    for (int kh = 0; kh < 3; ++kh) {
        #pragma unroll
        for (int kw = 0; kw < 3; ++kw) {
            int ih = h + kh - 1, iw = w + kw - 1;
            bool valid = ((unsigned)ih < HH) && ((unsigned)iw < WW);
            int ihc = min(max(ih, 0), HH - 1);
            int iwc = min(max(iw, 0), WW - 1);
            const float* xp   = xb + ihc * WW + iwc;
            const float* wrow = keff + (kh * 3 + kw) * (CC * OO) + ocb;
            const float* cfp  = coef + (kh * 3 + kw) * CC;
            float fm = valid ? 1.0f : 0.0f;
            #pragma unroll 4
            for (int c = 0; c < CC; ++c) {
                float xv = quant_x(xp[c * HWSZ]) * fm;
                s2 = fmaf(xv * xv, cfp[c], s2);
                #pragma unroll
                for (int i = 0; i < 16; ++i)
                    acc[i] = fmaf(xv, wrow[c * OO + i], acc[i]);
            }
        }
    }
    float* op = out + (size_t)b * (OO * HWSZ) + (size_t)ocb * HWSZ + rem;
    #pragma unroll
    for (int i = 0; i < 16; ++i)
        op[i * HWSZ] = acc[i] + s2 + wterm[ocb + i];
}

// ================= host launcher =================
extern "C" void kernel_launch(void* const* d_in, const int* in_sizes, int n_in,
                              void* d_out, int out_size, void* d_ws, size_t ws_size,
                              hipStream_t stream) {
    const float* x      = (const float*)d_in[0];
    const float* weight = (const float*)d_in[1];
    const float* phases = (const float*)d_in[2];
    const float* disks  = (const float*)d_in[3];
    float* out = (float*)d_out;

    char* ws = (char*)d_ws;
    unsigned* maxbits = (unsigned*)(ws + MAXB_OFF);
    unsigned* cflag   = (unsigned*)(ws + CFLAG_OFF);
    float* wterm = (float*)(ws + WTERM_OFF);
    float* coef  = (float*)(ws + COEF_OFF);

    hipMemsetAsync(ws, 0, 1280, stream);   // maxbits + cflag + wterm
    kmax_kernel<<<288, 256, 0, stream>>>(weight, maxbits);

    if (ws_size >= WS_NEED) {
        unsigned short* kefft = (unsigned short*)(ws + KEFF_OFF);
        float* ysq = (float*)(ws + YSQ_OFF);
        unsigned short* xqp = (unsigned short*)(ws + XQP_OFF);

        // allow 72KB dynamic LDS (idempotent; host-side, graph-capture-safe)
        hipFuncSetAttribute((const void*)oconv_kernel,
                            hipFuncAttributeMaxDynamicSharedMemorySize, 73728);

        kprep_kernel<<<(WELEM + 255) / 256, 256, 0, stream>>>(weight, phases, disks,
                                                              maxbits, kefft, coef, cflag, wterm);
        kborder_kernel<<<dim3(36, BB), 256, 0, stream>>>(xqp);
        kxqpad_kernel<<<dim3(49, BB), 256, 0, stream>>>(x, xqp);
        ysq_kernel<<<NPIX / 256, 256, 0, stream>>>(x, coef, cflag, ysq);
        oconv_kernel<<<dim3(392, 8), 256, 73728, stream>>>(xqp, kefft, ysq, wterm, out);
    } else {
        float* keff32 = (float*)(ws + KEFF32_OFF);
        kprep32_kernel<<<(WELEM + 255) / 256, 256, 0, stream>>>(weight, phases, disks,
                                                                maxbits, keff32, coef, wterm);
        kconv32_kernel<<<dim3(NPIX / 256, OO / 16), 256, 0, stream>>>(x, keff32, coef, wterm, out);
    }
}

// Round 7
// 225.129 us; speedup vs baseline: 1.6889x; 1.6889x over previous
//
#include <hip/hip_runtime.h>
#include <math.h>

typedef __attribute__((ext_vector_type(8))) short short8;
typedef __attribute__((ext_vector_type(4))) float floatx4;

#define BB 32
#define CC 128
#define OO 256
#define HH 56
#define WW 56
#define HWSZ 3136
#define NPIX 100352
#define WELEM 294912
#define QN 65535.0f
#define QINV (1.0f/65535.0f)

// xqp: bf16 [32][58 h][64 w][128 c]; per-batch stride in SHORTS:
#define XQP_BSTRIDE 475136            // 58*64*128 shorts = 950272 bytes

// ---- workspace layout (bytes) ----
#define MAXB_OFF   0
#define CFLAG_OFF  128                 // uint: any coef != 0 ?
#define WTERM_OFF  256
#define COEF_OFF   2048                // float [9][128]
#define KEFF_OFF   8192                // bf16 frag-order [36 steps][2 ot][8KB] = 589824 B
#define YSQ_OFF    598016              // float [100352] = 401408 B
#define XQP_OFF    1048576             // 30408704 B
#define XQP_BYTES  30408704ull
#define WS_NEED    (XQP_OFF + XQP_BYTES)
// fallback layout
#define KEFF32_OFF 8192                // float [9*128][256] = 1179648

// fused-prep role block ranges
#define NB_PREP 1152
#define NB_BORD 1152
#define NB_XQ   1568
#define NB_YSQ  392
#define NB_TOTAL (NB_PREP + NB_BORD + NB_XQ + NB_YSQ)

__device__ __forceinline__ float quant_x(float v) {
    v = fminf(fmaxf(v, 0.0f), 1.0f);
    return rintf(v * QN) * QINV;       // round-half-even == jnp.round
}

__device__ __forceinline__ unsigned short f2bf(float f) {
    unsigned u = __float_as_uint(f);
    u += 0x7fffu + ((u >> 16) & 1u);   // RNE
    return (unsigned short)(u >> 16);
}

__device__ __forceinline__ void gl16(const void* g, void* l) {
    __builtin_amdgcn_global_load_lds(
        (const __attribute__((address_space(1))) unsigned char*)g,
        (__attribute__((address_space(3))) unsigned char*)l, 16, 0, 0);
}

// ---------- kernel A: max |w| (blocks 0..287) + coef/cflag (block 288) ----------
__global__ void kmaxcoef_kernel(const float* __restrict__ w, const float* __restrict__ disks,
                                unsigned* __restrict__ maxout, float* __restrict__ coef,
                                unsigned* __restrict__ cflag) {
    if (blockIdx.x == 288) {
        int t = threadIdx.x;
        unsigned any = 0;
        for (int i = t; i < 9 * CC; i += 256) {       // i = kk*CC + c
            int kk = i >> 7, c = i & (CC - 1);
            int pidx = c * 9 + kk;
            float d0 = disks[pidx * 2 + 0], d1 = disks[pidx * 2 + 1];
            float cf = (d0 - d1) * 0.25f;
            coef[i] = cf;
            if (cf != 0.0f) any = 1;
        }
        if (any) atomicOr(cflag, 1u);
        return;
    }
    int i = blockIdx.x * blockDim.x + threadIdx.x;
    float m = 0.0f;
    for (int idx = i; idx < WELEM; idx += 288 * 256)
        m = fmaxf(m, fabsf(w[idx]));
    #pragma unroll
    for (int off = 32; off; off >>= 1)
        m = fmaxf(m, __shfl_down(m, off));
    __shared__ float red[4];
    if ((threadIdx.x & 63) == 0) red[threadIdx.x >> 6] = m;
    __syncthreads();
    if (threadIdx.x == 0) {
        m = fmaxf(fmaxf(red[0], red[1]), fmaxf(red[2], red[3]));
        atomicMax(maxout, __float_as_uint(m));   // all >= 0: uint order == float order
    }
}

// ---------- kernel B: role-fused prep ----------
// roles by blockIdx.x: [0,1152) kprep | [1152,2304) border | [2304,3872) xqpad | [3872,4264) ysq
__global__ __launch_bounds__(256) void kfused_kernel(
        const float* __restrict__ x, const float* __restrict__ wt,
        const float* __restrict__ phases, const float* __restrict__ disks,
        const unsigned* __restrict__ maxbits, const unsigned* __restrict__ cflag,
        const float* __restrict__ coef,
        unsigned short* __restrict__ kefft, float* __restrict__ wterm,
        unsigned short* __restrict__ xqp, float* __restrict__ ysq) {
    __shared__ __align__(16) char shmem[17408];      // xqpad tile [64][136] shorts / ysq cf
    const int bid = blockIdx.x;
    const int t   = threadIdx.x;

    if (bid < NB_PREP) {
        // ---- kprep: bf16 k_eff in MFMA-fragment order + w_term ----
        // step s = kk*4 + (c>>5); per (step, ot) 8KB tile:
        //   byte = wm*4096 + mf*1024 + (kg*16 + l15)*16 + e*2
        int idx = bid * 256 + t;                      // over [o][c][kh][kw], exact
        int kk = idx % 9;
        int c  = (idx / 9) % CC;
        int o  = idx / (9 * CC);
        float M = tanhf(__uint_as_float(*maxbits));
        float tv = tanhf(wt[idx]);
        float v = tv / (2.0f * M) + 0.5f;
        float wq = rintf(v * QN) * QINV;
        int pidx = c * 9 + kk;
        float s  = sinf(phases[pidx]);
        float d0 = disks[pidx * 2 + 0];
        float d1 = disks[pidx * 2 + 1];
        float kv = wq * (s * (d0 + d1) * 0.5f);
        int step = kk * 4 + (c >> 5);
        int ot = o >> 7, lo = o & 127;
        int wm = lo >> 6, mf = (lo >> 4) & 3, l15 = lo & 15;
        int kg = (c >> 3) & 3, e = c & 7;
        size_t byte = (size_t)(step * 2 + ot) * 8192
                    + wm * 4096 + mf * 1024 + (kg * 16 + l15) * 16 + e * 2;
        kefft[byte >> 1] = f2bf(kv);
        float cf = (d0 - d1) * 0.25f;
        float contrib = wq * wq * cf;
        if (contrib != 0.0f) atomicAdd(wterm + o, contrib);
        return;
    }

    if (bid < NB_PREP + NB_BORD) {
        // ---- border zero: 576 border px * 16 chunks = 9216 ids per batch ----
        int flat = bid - NB_PREP;                     // [0,1152)
        int b   = flat / 36;
        int id  = (flat % 36) * 256 + t;              // [0,9216)
        int pxi = id >> 4, chunk = id & 15;
        int h, w;
        if (pxi < 128) { h = (pxi >> 6) * 57; w = pxi & 63; }
        else { int r = pxi - 128; h = 1 + (r >> 3); int wi = r & 7; w = wi == 0 ? 0 : 56 + wi; }
        short8 z = (short8)0;
        *reinterpret_cast<short8*>((char*)xqp + (size_t)b * (XQP_BSTRIDE * 2)
                                   + ((size_t)(h * 64 + w)) * 256 + chunk * 16) = z;
        return;
    }

    if (bid < NB_PREP + NB_BORD + NB_XQ) {
        // ---- quantize + NCHW->padded-NHWC bf16 transpose (float4 loads) ----
        int id3 = bid - (NB_PREP + NB_BORD);
        int bx = id3 % 49, b = id3 / 49;
        int hw0 = bx * 64;
        unsigned short (*tile)[136] = (unsigned short (*)[136])shmem;  // [hw][c]
        const float* xb = x + (size_t)b * (CC * HWSZ) + hw0;
        #pragma unroll
        for (int rep = 0; rep < 8; ++rep) {
            int lin = rep * 256 + t;
            int c = lin >> 4, j4 = lin & 15;
            float4 v = *reinterpret_cast<const float4*>(xb + (size_t)c * HWSZ + j4 * 4);
            tile[j4 * 4 + 0][c] = f2bf(quant_x(v.x));
            tile[j4 * 4 + 1][c] = f2bf(quant_x(v.y));
            tile[j4 * 4 + 2][c] = f2bf(quant_x(v.z));
            tile[j4 * 4 + 3][c] = f2bf(quant_x(v.w));
        }
        __syncthreads();
        unsigned short* xq_b = xqp + (size_t)b * XQP_BSTRIDE;
        #pragma unroll
        for (int rep = 0; rep < 4; ++rep) {
            int lin = rep * 256 + t;
            int c16 = lin & 15, j = lin >> 4;
            int hw = hw0 + j;
            int h = hw / WW, w = hw - h * WW;
            short8 v = *reinterpret_cast<const short8*>(&tile[j][c16 * 8]);
            *reinterpret_cast<short8*>(xq_b + ((size_t)((h + 1) * 64 + (w + 1))) * 128 + c16 * 8) = v;
        }
        return;
    }

    // ---- y_sq = conv(x_q^2, coef); skip entirely when all coef==0 ----
    {
        if (*cflag == 0u) return;                     // oconv adds 0 in this case
        float* cf = (float*)shmem;
        for (int i = t; i < 9 * CC; i += 256) cf[i] = coef[i];
        __syncthreads();
        int P = (bid - (NB_PREP + NB_BORD + NB_XQ)) * 256 + t;
        int b = P / HWSZ; int hw = P - b * HWSZ;
        int h = hw / WW;  int w = hw - h * WW;
        const float* xb = x + (size_t)b * (CC * HWSZ);
        float s2 = 0.0f;
        #pragma unroll
        for (int kk = 0; kk < 9; ++kk) {
            int dh = kk / 3 - 1, dw = kk % 3 - 1;
            int ih = h + dh, iw = w + dw;
            bool valid = ((unsigned)ih < HH) && ((unsigned)iw < WW);
            int ihc = min(max(ih, 0), HH - 1), iwc = min(max(iw, 0), WW - 1);
            const float* xp = xb + ihc * WW + iwc;
            float fm = valid ? 1.0f : 0.0f;
            const float* cp = cf + kk * CC;
            #pragma unroll 4
            for (int c = 0; c < CC; ++c) {
                float xv = quant_x(xp[(size_t)c * HWSZ]) * fm;
                s2 = fmaf(xv * xv, cp[c], s2);
            }
        }
        ysq[P] = s2;
    }
}

// ---------- MFMA implicit-GEMM conv: BK=32, counted-vmcnt depth-2 pipeline (R5) ----------
__global__ __launch_bounds__(256, 2) void oconv_kernel(
        const unsigned short* __restrict__ xqp,
        const unsigned short* __restrict__ keff,
        const float* __restrict__ ysq,
        const float* __restrict__ wterm,
        const unsigned* __restrict__ cflag,
        float* __restrict__ out) {
    __shared__ __align__(16) char smem[32768];
    const int t  = threadIdx.x;
    // XCD-pair swizzle: 1568 = 8 * 196; pair (2k,2k+1) shares the B tile on one XCD.
    const int id  = blockIdx.x;
    const int swz = (id & 7) * 196 + (id >> 3);
    const int bx  = swz >> 1;                    // pixel tile (784)
    const int oty = swz & 1;                     // o tile (2)
    const bool use_ysq = (*cflag != 0u);

    const char* xb = (const char*)xqp;
    long bb0, bb1;
    {
        int pxA  = ((t >> 6) << 4) + (t & 15);
        int cOff = ((t >> 4) & 3) * 16;
        int P0 = bx * 128 + pxA;
        int b0 = P0 / HWSZ, hw0 = P0 - b0 * HWSZ;
        int h0 = hw0 / WW,  w0 = hw0 - h0 * WW;
        bb0 = ((long)((b0 * 58 + h0 + 1) * 64 + (w0 + 1))) * 256 + cOff;
        int P1 = P0 + 64;
        int b1 = P1 / HWSZ, hw1 = P1 - b1 * HWSZ;
        int h1 = hw1 / WW,  w1 = hw1 - h1 * WW;
        bb1 = ((long)((b1 * 58 + h1 + 1) * 64 + (w1 + 1))) * 256 + cOff;
    }

    const int l15 = t & 15;
    const int kg  = (t >> 4) & 3;
    const int wid = t >> 6;
    const int wm  = wid >> 1, wn = wid & 1;
    const int lane16 = (t & 63) * 16;

    floatx4 acc[4][4];
    #pragma unroll
    for (int i = 0; i < 4; ++i)
        #pragma unroll
        for (int j = 0; j < 4; ++j) acc[i][j] = (floatx4)0.0f;

    auto stage = [&](int buf, int s) {
        char* la = smem + buf * 16384 + t * 16;
        const char* ga = (const char*)keff + (size_t)(s * 2 + oty) * 8192 + t * 16;
        gl16(ga,        la);
        gl16(ga + 4096, la + 4096);
        int kk = s >> 2, cs = s & 3;
        int dh = kk / 3, dw = kk - dh * 3;
        long bo = (long)((dh - 1) * 64 + (dw - 1)) * 256 + cs * 64;
        char* lb = la + 8192;
        gl16(xb + bb0 + bo, lb);
        gl16(xb + bb1 + bo, lb + 4096);
    };

    auto compute = [&](int buf) {
        const char* base = smem + buf * 16384;
        const char* ap = base + wm * 4096 + lane16;
        const char* bp = base + 8192 + wn * 4096 + lane16;
        short8 a[4], b[4];
        #pragma unroll
        for (int mf = 0; mf < 4; ++mf)
            a[mf] = *reinterpret_cast<const short8*>(ap + mf * 1024);
        #pragma unroll
        for (int nf = 0; nf < 4; ++nf)
            b[nf] = *reinterpret_cast<const short8*>(bp + nf * 1024);
        #pragma unroll
        for (int mf = 0; mf < 4; ++mf)
            #pragma unroll
            for (int nf = 0; nf < 4; ++nf)
                acc[mf][nf] = __builtin_amdgcn_mfma_f32_16x16x32_bf16(a[mf], b[nf], acc[mf][nf], 0, 0, 0);
    };

    stage(0, 0);
    stage(1, 1);
    for (int s = 0; s < 36; ++s) {
        if (s < 35) { asm volatile("s_waitcnt vmcnt(4)" ::: "memory"); }
        else        { asm volatile("s_waitcnt vmcnt(0)" ::: "memory"); }
        __builtin_amdgcn_sched_barrier(0);
        __builtin_amdgcn_s_barrier();        // batch s resident for all waves
        compute(s & 1);
        asm volatile("s_waitcnt lgkmcnt(0)" ::: "memory");
        __builtin_amdgcn_sched_barrier(0);
        __builtin_amdgcn_s_barrier();        // all reads of buffer s&1 done
        if (s < 34) stage(s & 1, s + 2);     // overwrite just-read buffer
    }

    // --- epilogue: D row = o (row=(lane>>4)*4+reg), col = pixel (col=lane&15) ---
    float wv[4][4];
    #pragma unroll
    for (int mf = 0; mf < 4; ++mf)
        #pragma unroll
        for (int j = 0; j < 4; ++j)
            wv[mf][j] = wterm[oty * 128 + wm * 64 + mf * 16 + kg * 4 + j];

    #pragma unroll
    for (int nf = 0; nf < 4; ++nf) {
        int P = bx * 128 + wn * 64 + nf * 16 + l15;
        int b = P / HWSZ; int hw = P - b * HWSZ;
        float yv = 0.0f;
        if (use_ysq) yv = ysq[P];
        float* op = out + (size_t)b * (OO * HWSZ) + hw;
        #pragma unroll
        for (int mf = 0; mf < 4; ++mf)
            #pragma unroll
            for (int j = 0; j < 4; ++j) {
                int o = oty * 128 + wm * 64 + mf * 16 + kg * 4 + j;
                op[(size_t)o * HWSZ] = acc[mf][nf][j] + yv + wv[mf][j];
            }
    }
}

// ================= fallback path (fp32 direct conv) =================
__global__ void kprep32_kernel(const float* __restrict__ wt, const float* __restrict__ phases,
                               const float* __restrict__ disks, const unsigned* __restrict__ maxbits,
                               float* __restrict__ keff, float* __restrict__ coef,
                               float* __restrict__ wterm) {
    int idx = blockIdx.x * blockDim.x + threadIdx.x;
    if (idx >= WELEM) return;
    int kk = idx % 9;
    int c  = (idx / 9) % CC;
    int o  = idx / (9 * CC);
    float M = tanhf(__uint_as_float(*maxbits));
    float t = tanhf(wt[idx]);
    float v = t / (2.0f * M) + 0.5f;
    float wq = rintf(v * QN) * QINV;
    int pidx = c * 9 + kk;
    float s  = sinf(phases[pidx]);
    float d0 = disks[pidx * 2 + 0];
    float d1 = disks[pidx * 2 + 1];
    keff[(kk * CC + c) * OO + o] = wq * (s * (d0 + d1) * 0.5f);
    float cf = (d0 - d1) * 0.25f;
    if (o == 0) coef[kk * CC + c] = cf;
    float contrib = wq * wq * cf;
    if (contrib != 0.0f) atomicAdd(wterm + o, contrib);
}

__global__ __launch_bounds__(256) void kconv32_kernel(
        const float* __restrict__ xsrc, const float* __restrict__ keff,
        const float* __restrict__ coef, const float* __restrict__ wterm,
        float* __restrict__ out) {
    int t   = blockIdx.x * 256 + threadIdx.x;
    int ocb = blockIdx.y * 16;
    int b   = t / HWSZ;
    int rem = t - b * HWSZ;
    int h   = rem / WW;
    int w   = rem - h * WW;
    float acc[16];
    #pragma unroll
    for (int i = 0; i < 16; ++i) acc[i] = 0.0f;
    float s2 = 0.0f;
    const float* xb = xsrc + (size_t)b * (CC * HWSZ);
    #pragma unroll
    for (int kh = 0; kh < 3; ++kh) {
        #pragma unroll
        for (int kw = 0; kw < 3; ++kw) {
            int ih = h + kh - 1, iw = w + kw - 1;
            bool valid = ((unsigned)ih < HH) && ((unsigned)iw < WW);
            int ihc = min(max(ih, 0), HH - 1);
            int iwc = min(max(iw, 0), WW - 1);
            const float* xp   = xb + ihc * WW + iwc;
            const float* wrow = keff + (kh * 3 + kw) * (CC * OO) + ocb;
            const float* cfp  = coef + (kh * 3 + kw) * CC;
            float fm = valid ? 1.0f : 0.0f;
            #pragma unroll 4
            for (int c = 0; c < CC; ++c) {
                float xv = quant_x(xp[c * HWSZ]) * fm;
                s2 = fmaf(xv * xv, cfp[c], s2);
                #pragma unroll
                for (int i = 0; i < 16; ++i)
                    acc[i] = fmaf(xv, wrow[c * OO + i], acc[i]);
            }
        }
    }
    float* op = out + (size_t)b * (OO * HWSZ) + (size_t)ocb * HWSZ + rem;
    #pragma unroll
    for (int i = 0; i < 16; ++i)
        op[i * HWSZ] = acc[i] + s2 + wterm[ocb + i];
}

// ================= host launcher =================
extern "C" void kernel_launch(void* const* d_in, const int* in_sizes, int n_in,
                              void* d_out, int out_size, void* d_ws, size_t ws_size,
                              hipStream_t stream) {
    const float* x      = (const float*)d_in[0];
    const float* weight = (const float*)d_in[1];
    const float* phases = (const float*)d_in[2];
    const float* disks  = (const float*)d_in[3];
    float* out = (float*)d_out;

    char* ws = (char*)d_ws;
    unsigned* maxbits = (unsigned*)(ws + MAXB_OFF);
    unsigned* cflag   = (unsigned*)(ws + CFLAG_OFF);
    float* wterm = (float*)(ws + WTERM_OFF);
    float* coef  = (float*)(ws + COEF_OFF);

    hipMemsetAsync(ws, 0, 1280, stream);   // maxbits + cflag + wterm

    if (ws_size >= WS_NEED) {
        unsigned short* kefft = (unsigned short*)(ws + KEFF_OFF);
        float* ysq = (float*)(ws + YSQ_OFF);
        unsigned short* xqp = (unsigned short*)(ws + XQP_OFF);

        kmaxcoef_kernel<<<289, 256, 0, stream>>>(weight, disks, maxbits, coef, cflag);
        kfused_kernel<<<NB_TOTAL, 256, 0, stream>>>(x, weight, phases, disks, maxbits,
                                                    cflag, coef, kefft, wterm, xqp, ysq);
        oconv_kernel<<<1568, 256, 0, stream>>>(xqp, kefft, ysq, wterm, cflag, out);
    } else {
        float* keff32 = (float*)(ws + KEFF32_OFF);
        kmaxcoef_kernel<<<289, 256, 0, stream>>>(weight, disks, maxbits, coef, cflag);
        kprep32_kernel<<<(WELEM + 255) / 256, 256, 0, stream>>>(weight, phases, disks,
                                                                maxbits, keff32, coef, wterm);
        kconv32_kernel<<<dim3(NPIX / 256, OO / 16), 256, 0, stream>>>(x, keff32, coef, wterm, out);
    }
}